// Round 1
// baseline (1781.752 us; speedup 1.0000x reference)
//
#include <hip/hip_runtime.h>
#include <math.h>

#define IN_F  128
#define HID   96
#define OUT_F 40
#define MASKD 64

// ---------------- degree / dinv ----------------
__global__ void k_deg_init(float* __restrict__ deg, int n) {
    int i = blockIdx.x * blockDim.x + threadIdx.x;
    if (i < n) deg[i] = 1.0f;  // self-loop contributes 1 to every node's degree
}

__global__ void k_deg_scatter(const int* __restrict__ dst, float* __restrict__ deg, int e) {
    int i = blockIdx.x * blockDim.x + threadIdx.x;
    if (i < e) atomicAdd(&deg[dst[i]], 1.0f);
}

__global__ void k_dinv(float* __restrict__ deg, int n) {
    int i = blockIdx.x * blockDim.x + threadIdx.x;
    if (i < n) deg[i] = 1.0f / sqrtf(deg[i]);   // deg >= 1 always
}

// ---------------- GEMM1: hs = (x @ W1) * dinv[row]; h initialized to hs (self-loop term) ----------------
__global__ __launch_bounds__(256) void k_gemm1(const float* __restrict__ x,
                                               const float* __restrict__ W1,
                                               const float* __restrict__ dinv,
                                               float* __restrict__ hs,
                                               float* __restrict__ h, int n) {
    __shared__ float sW[IN_F * HID];   // 48 KB
    __shared__ float sx[16][IN_F];     // 8 KB
    int tid = threadIdx.x;
    for (int i = tid; i < IN_F * HID; i += 256) sW[i] = W1[i];
    int base = blockIdx.x * 16;
    if (base >= n) return;             // block-uniform, safe w.r.t. barriers
    int nt = min(16, n - base);
    __syncthreads();
    for (int i = tid; i < nt * IN_F; i += 256)
        sx[i >> 7][i & 127] = x[(size_t)(base + (i >> 7)) * IN_F + (i & 127)];
    __syncthreads();

    int c = tid & 127;        // column (0..95 active)
    int half = tid >> 7;      // 0..1 -> node sub-range
    if (c < HID) {
        int n_lo = half * 8, n_hi = min(half * 8 + 8, nt);
        for (int n0 = n_lo; n0 < n_hi; n0 += 4) {
            int m = min(4, n_hi - n0);
            if (m == 4) {
                float a0 = 0.f, a1 = 0.f, a2 = 0.f, a3 = 0.f;
#pragma unroll 16
                for (int k = 0; k < IN_F; k++) {
                    float w = sW[k * HID + c];
                    a0 += sx[n0 + 0][k] * w;
                    a1 += sx[n0 + 1][k] * w;
                    a2 += sx[n0 + 2][k] * w;
                    a3 += sx[n0 + 3][k] * w;
                }
                float acc[4] = {a0, a1, a2, a3};
#pragma unroll
                for (int j = 0; j < 4; j++) {
                    int node = base + n0 + j;
                    float v = acc[j] * dinv[node];
                    size_t o = (size_t)node * HID + c;
                    hs[o] = v;
                    h[o] = v;
                }
            } else {
                for (int j = 0; j < m; j++) {
                    float a = 0.f;
#pragma unroll 16
                    for (int k = 0; k < IN_F; k++) a += sx[n0 + j][k] * sW[k * HID + c];
                    int node = base + n0 + j;
                    float v = a * dinv[node];
                    size_t o = (size_t)node * HID + c;
                    hs[o] = v;
                    h[o] = v;
                }
            }
        }
    }
}

// ---------------- scatter layer 1: h[dst] += hs[src], 96 floats/edge via float4 ----------------
__global__ __launch_bounds__(256) void k_scatter1(const int* __restrict__ src,
                                                  const int* __restrict__ dst,
                                                  const float* __restrict__ hs,
                                                  float* __restrict__ h, int e) {
    int t = blockIdx.x * 256 + threadIdx.x;
    int eidx = t >> 5;          // 8 edges per 256-block
    int cg = t & 31;            // 24 active float4 column-groups
    if (eidx >= e || cg >= 24) return;
    int s = src[eidx], d = dst[eidx];
    const float4 v = *(const float4*)(hs + (size_t)s * HID + cg * 4);
    float* p = h + (size_t)d * HID + cg * 4;
    atomicAdd(p + 0, v.x);
    atomicAdd(p + 1, v.y);
    atomicAdd(p + 2, v.z);
    atomicAdd(p + 3, v.w);
}

// ---------------- h = relu(h * dinv[row] + b1) ----------------
__global__ void k_relu_eps(float* __restrict__ h, const float* __restrict__ dinv,
                           const float* __restrict__ b1, int n) {
    int i = blockIdx.x * blockDim.x + threadIdx.x;
    if (i < n * HID) {
        int nn = i / HID, c = i - nn * HID;
        h[i] = fmaxf(h[i] * dinv[nn] + b1[c], 0.0f);
    }
}

// ---------------- GEMM2: zs = (h @ W2) * dinv[row]; z initialized to zs ----------------
__global__ __launch_bounds__(256) void k_gemm2(const float* __restrict__ hbuf,
                                               const float* __restrict__ W2,
                                               const float* __restrict__ dinv,
                                               float* __restrict__ zs,
                                               float* __restrict__ z, int n) {
    __shared__ float sW[HID * OUT_F];  // 15 KB
    __shared__ float sx[16][HID];      // 6 KB
    int tid = threadIdx.x;
    for (int i = tid; i < HID * OUT_F; i += 256) sW[i] = W2[i];
    int base = blockIdx.x * 16;
    if (base >= n) return;
    int nt = min(16, n - base);
    __syncthreads();
    for (int i = tid; i < nt * HID; i += 256)
        sx[i / HID][i % HID] = hbuf[(size_t)(base + i / HID) * HID + (i % HID)];
    __syncthreads();
    for (int idx = tid; idx < nt * OUT_F; idx += 256) {
        int nn = idx / OUT_F, cc = idx - nn * OUT_F;
        float acc = 0.f;
#pragma unroll
        for (int k = 0; k < HID; k++) acc += sx[nn][k] * sW[k * OUT_F + cc];
        int node = base + nn;
        float v = acc * dinv[node];
        size_t o = (size_t)node * OUT_F + cc;
        zs[o] = v;
        z[o] = v;
    }
}

// ---------------- scatter layer 2: z[dst] += zs[src], 40 floats/edge ----------------
__global__ __launch_bounds__(256) void k_scatter2(const int* __restrict__ src,
                                                  const int* __restrict__ dst,
                                                  const float* __restrict__ zs,
                                                  float* __restrict__ z, int e) {
    int t = blockIdx.x * 256 + threadIdx.x;
    int eidx = t >> 4;          // 16 edges per 256-block
    int cg = t & 15;            // 10 active float4 column-groups
    if (eidx >= e || cg >= 10) return;
    int s = src[eidx], d = dst[eidx];
    const float4 v = *(const float4*)(zs + (size_t)s * OUT_F + cg * 4);
    float* p = z + (size_t)d * OUT_F + cg * 4;
    atomicAdd(p + 0, v.x);
    atomicAdd(p + 1, v.y);
    atomicAdd(p + 2, v.z);
    atomicAdd(p + 3, v.w);
}

// ---------------- logits = log_softmax(z * dinv[row] + b2) ----------------
__global__ __launch_bounds__(256) void k_logsoftmax(const float* __restrict__ z,
                                                    const float* __restrict__ dinv,
                                                    const float* __restrict__ b2,
                                                    float* __restrict__ out, int n) {
    int lane = threadIdx.x & 63;
    int node = blockIdx.x * 4 + (threadIdx.x >> 6);
    if (node >= n) return;
    float v = -INFINITY;
    if (lane < OUT_F) v = z[(size_t)node * OUT_F + lane] * dinv[node] + b2[lane];
    float m = v;
    for (int off = 32; off; off >>= 1) m = fmaxf(m, __shfl_xor(m, off));
    float ex = (lane < OUT_F) ? expf(v - m) : 0.0f;
    float s = ex;
    for (int off = 32; off; off >>= 1) s += __shfl_xor(s, off);
    float ls = logf(s);
    if (lane < OUT_F) out[(size_t)node * OUT_F + lane] = v - m - ls;
}

// ---------------- mask MLP: prob = sigmoid(relu(h@Wm1+bm1)@Wm2+bm2); mask = prob>0.5 ----------------
__global__ __launch_bounds__(256) void k_mask(const float* __restrict__ h,
                                              const float* __restrict__ Wm1,
                                              const float* __restrict__ bm1,
                                              const float* __restrict__ Wm2,
                                              const float* __restrict__ bm2,
                                              float* __restrict__ prob_out,
                                              float* __restrict__ mask_out, int n) {
    __shared__ float sW[HID * MASKD];  // 24 KB
    __shared__ float sh[4][HID];
    int tid = threadIdx.x;
    for (int i = tid; i < HID * MASKD; i += 256) sW[i] = Wm1[i];
    int wv = tid >> 6, lane = tid & 63;
    int nb = blockIdx.x * 4;
    if (nb >= n) return;
    int nt = min(4, n - nb);
    __syncthreads();
    for (int i = tid; i < nt * HID; i += 256)
        sh[i / HID][i % HID] = h[(size_t)(nb + i / HID) * HID + (i % HID)];
    __syncthreads();
    if (wv < nt) {
        float acc = bm1[lane];
#pragma unroll
        for (int k = 0; k < HID; k++) acc += sh[wv][k] * sW[k * MASKD + lane];
        float mrelu = fmaxf(acc, 0.0f);
        float part = mrelu * Wm2[lane];
        for (int off = 32; off; off >>= 1) part += __shfl_xor(part, off);
        if (lane == 0) {
            float t = part + bm2[0];
            float p = 1.0f / (1.0f + expf(-t));
            prob_out[nb + wv] = p;
            mask_out[nb + wv] = (p > 0.5f) ? 1.0f : 0.0f;
        }
    }
}

extern "C" void kernel_launch(void* const* d_in, const int* in_sizes, int n_in,
                              void* d_out, int out_size, void* d_ws, size_t ws_size,
                              hipStream_t stream) {
    const float* x   = (const float*)d_in[0];
    const int*   ei  = (const int*)d_in[1];
    const float* W1  = (const float*)d_in[2];
    const float* b1  = (const float*)d_in[3];
    const float* W2  = (const float*)d_in[4];
    const float* b2  = (const float*)d_in[5];
    const float* Wm1 = (const float*)d_in[6];
    const float* bm1 = (const float*)d_in[7];
    const float* Wm2 = (const float*)d_in[8];
    const float* bm2 = (const float*)d_in[9];

    int n = in_sizes[0] / IN_F;      // 50000
    int e = in_sizes[1] / 2;         // 800000
    const int* srcp = ei;            // edge_index[0]
    const int* dstp = ei + e;        // edge_index[1]

    float* ws   = (float*)d_ws;
    float* dinv = ws;                             // N        (deg, then rsqrt in place)
    float* hs   = dinv + n;                       // N*96     (pre-scaled linear output)
    float* h    = hs + (size_t)n * HID;           // N*96     (aggregation accumulator -> relu'd h)
    float* zs   = h + (size_t)n * HID;            // N*40
    float* z    = zs + (size_t)n * OUT_F;         // N*40

    float* out    = (float*)d_out;
    float* logits = out;                          // N*40
    float* prob   = out + (size_t)n * OUT_F;      // N
    float* mask   = prob + n;                     // N

    k_deg_init   <<<(n + 255) / 256, 256, 0, stream>>>(dinv, n);
    k_deg_scatter<<<(e + 255) / 256, 256, 0, stream>>>(dstp, dinv, e);
    k_dinv       <<<(n + 255) / 256, 256, 0, stream>>>(dinv, n);
    k_gemm1      <<<(n + 15) / 16, 256, 0, stream>>>(x, W1, dinv, hs, h, n);
    k_scatter1   <<<(e * 32 + 255) / 256, 256, 0, stream>>>(srcp, dstp, hs, h, e);
    k_relu_eps   <<<(n * HID + 255) / 256, 256, 0, stream>>>(h, dinv, b1, n);
    k_gemm2      <<<(n + 15) / 16, 256, 0, stream>>>(h, W2, dinv, zs, z, n);
    k_scatter2   <<<(e * 16 + 255) / 256, 256, 0, stream>>>(srcp, dstp, zs, z, e);
    k_logsoftmax <<<(n + 3) / 4, 256, 0, stream>>>(z, dinv, b2, logits, n);
    k_mask       <<<(n + 3) / 4, 256, 0, stream>>>(h, Wm1, bm1, Wm2, bm2, prob, mask, n);
}

// Round 2
// 414.149 us; speedup vs baseline: 4.3022x; 4.3022x over previous
//
#include <hip/hip_runtime.h>
#include <math.h>

#define IN_F  128
#define HID   96
#define OUT_F 40
#define MASKD 64

// ======================= CSR construction =======================
__global__ void k_zero_int(int* __restrict__ p, int n) {
    int i = blockIdx.x * blockDim.x + threadIdx.x;
    if (i < n) p[i] = 0;
}

__global__ void k_count(const int* __restrict__ dst, int* __restrict__ deg, int e) {
    int i = blockIdx.x * blockDim.x + threadIdx.x;
    if (i < e) atomicAdd(&deg[dst[i]], 1);
}

// dinv[i] = rsqrt(deg_edges[i] + 1)   (+1 = self-loop)
__global__ void k_dinv(const int* __restrict__ deg, float* __restrict__ dinv, int n) {
    int i = blockIdx.x * blockDim.x + threadIdx.x;
    if (i < n) dinv[i] = rsqrtf((float)(deg[i] + 1));
}

// two-level exclusive scan (n <= 256*256 assumed; n=50000 here)
__global__ void k_scan1(const int* __restrict__ deg, int* __restrict__ offs,
                        int* __restrict__ bsum, int n) {
    __shared__ int tmp[256];
    int i = blockIdx.x * 256 + threadIdx.x;
    int v = (i < n) ? deg[i] : 0;
    tmp[threadIdx.x] = v;
    __syncthreads();
    for (int d = 1; d < 256; d <<= 1) {
        int t = (threadIdx.x >= d) ? tmp[threadIdx.x - d] : 0;
        __syncthreads();
        tmp[threadIdx.x] += t;
        __syncthreads();
    }
    if (i < n) offs[i] = tmp[threadIdx.x] - v;   // exclusive
    if (threadIdx.x == 255) bsum[blockIdx.x] = tmp[255];
}

__global__ void k_scan2(int* __restrict__ bsum, int nb) {
    __shared__ int tmp[256];
    int v = (threadIdx.x < nb) ? bsum[threadIdx.x] : 0;
    tmp[threadIdx.x] = v;
    __syncthreads();
    for (int d = 1; d < 256; d <<= 1) {
        int t = (threadIdx.x >= d) ? tmp[threadIdx.x - d] : 0;
        __syncthreads();
        tmp[threadIdx.x] += t;
        __syncthreads();
    }
    if (threadIdx.x < nb) bsum[threadIdx.x] = tmp[threadIdx.x] - v;  // exclusive
}

__global__ void k_scan3(int* __restrict__ offs, const int* __restrict__ bsum,
                        int* __restrict__ cursor, int n) {
    int i = blockIdx.x * 256 + threadIdx.x;
    if (i < n) {
        int o = offs[i] + bsum[blockIdx.x];
        offs[i] = o;
        cursor[i] = o;
    }
}

__global__ void k_fill(const int* __restrict__ src, const int* __restrict__ dst,
                       int* __restrict__ cursor, int* __restrict__ csr, int e) {
    int i = blockIdx.x * blockDim.x + threadIdx.x;
    if (i < e) {
        int pos = atomicAdd(&cursor[dst[i]], 1);
        csr[pos] = src[i];
    }
}

// ======================= GEMM1: hs = (x @ W1) * dinv[row] =======================
__global__ __launch_bounds__(256) void k_gemm1(const float* __restrict__ x,
                                               const float* __restrict__ W1,
                                               const float* __restrict__ dinv,
                                               float* __restrict__ hs, int n) {
    __shared__ float sW[IN_F * HID];   // 48 KB
    __shared__ float sx[16][IN_F];     // 8 KB
    int tid = threadIdx.x;
    for (int i = tid; i < IN_F * HID; i += 256) sW[i] = W1[i];
    int base = blockIdx.x * 16;
    if (base >= n) return;             // block-uniform
    int nt = min(16, n - base);
    __syncthreads();
    for (int i = tid; i < nt * IN_F; i += 256)
        sx[i >> 7][i & 127] = x[(size_t)(base + (i >> 7)) * IN_F + (i & 127)];
    __syncthreads();

    int c = tid & 127;        // column (0..95 active)
    int half = tid >> 7;
    if (c < HID) {
        int n_lo = half * 8, n_hi = min(half * 8 + 8, nt);
        for (int n0 = n_lo; n0 < n_hi; n0 += 4) {
            int m = min(4, n_hi - n0);
            if (m == 4) {
                float a0 = 0.f, a1 = 0.f, a2 = 0.f, a3 = 0.f;
#pragma unroll 16
                for (int k = 0; k < IN_F; k++) {
                    float w = sW[k * HID + c];
                    a0 += sx[n0 + 0][k] * w;
                    a1 += sx[n0 + 1][k] * w;
                    a2 += sx[n0 + 2][k] * w;
                    a3 += sx[n0 + 3][k] * w;
                }
                float acc[4] = {a0, a1, a2, a3};
#pragma unroll
                for (int j = 0; j < 4; j++) {
                    int node = base + n0 + j;
                    hs[(size_t)node * HID + c] = acc[j] * dinv[node];
                }
            } else {
                for (int j = 0; j < m; j++) {
                    float a = 0.f;
#pragma unroll 16
                    for (int k = 0; k < IN_F; k++) a += sx[n0 + j][k] * sW[k * HID + c];
                    int node = base + n0 + j;
                    hs[(size_t)node * HID + c] = a * dinv[node];
                }
            }
        }
    }
}

// ======================= gather layer 1: h[i] = hs[i] + sum_{s in N(i)} hs[s] =======================
__global__ __launch_bounds__(256) void k_gather1(const int* __restrict__ offs,
                                                 const int* __restrict__ deg,
                                                 const int* __restrict__ csr,
                                                 const float* __restrict__ hs,
                                                 float* __restrict__ h, int n) {
    int t = blockIdx.x * 256 + threadIdx.x;
    int node = t >> 5;          // 32 threads per node
    int cg = t & 31;            // 24 active float4 column-groups
    if (node >= n || cg >= 24) return;
    int o = offs[node], cnt = deg[node];
    size_t col = (size_t)cg * 4;
    float4 acc = *(const float4*)(hs + (size_t)node * HID + col);  // self-loop term
    int k = o, kend = o + cnt;
    for (; k + 1 < kend; k += 2) {
        int s0 = csr[k], s1 = csr[k + 1];
        const float4 v0 = *(const float4*)(hs + (size_t)s0 * HID + col);
        const float4 v1 = *(const float4*)(hs + (size_t)s1 * HID + col);
        acc.x += v0.x + v1.x; acc.y += v0.y + v1.y;
        acc.z += v0.z + v1.z; acc.w += v0.w + v1.w;
    }
    if (k < kend) {
        int s0 = csr[k];
        const float4 v0 = *(const float4*)(hs + (size_t)s0 * HID + col);
        acc.x += v0.x; acc.y += v0.y; acc.z += v0.z; acc.w += v0.w;
    }
    *(float4*)(h + (size_t)node * HID + col) = acc;
}

// ======================= h = relu(h * dinv[row] + b1) =======================
__global__ void k_relu_eps(float* __restrict__ h, const float* __restrict__ dinv,
                           const float* __restrict__ b1, int n) {
    int i = blockIdx.x * blockDim.x + threadIdx.x;
    if (i < n * HID) {
        int nn = i / HID, c = i - nn * HID;
        h[i] = fmaxf(h[i] * dinv[nn] + b1[c], 0.0f);
    }
}

// ======================= GEMM2: zs = (h @ W2) * dinv[row] =======================
__global__ __launch_bounds__(256) void k_gemm2(const float* __restrict__ hbuf,
                                               const float* __restrict__ W2,
                                               const float* __restrict__ dinv,
                                               float* __restrict__ zs, int n) {
    __shared__ float sW[HID * OUT_F];  // 15 KB
    __shared__ float sx[16][HID];      // 6 KB
    int tid = threadIdx.x;
    for (int i = tid; i < HID * OUT_F; i += 256) sW[i] = W2[i];
    int base = blockIdx.x * 16;
    if (base >= n) return;
    int nt = min(16, n - base);
    __syncthreads();
    for (int i = tid; i < nt * HID; i += 256)
        sx[i / HID][i % HID] = hbuf[(size_t)(base + i / HID) * HID + (i % HID)];
    __syncthreads();
    for (int idx = tid; idx < nt * OUT_F; idx += 256) {
        int nn = idx / OUT_F, cc = idx - nn * OUT_F;
        float acc = 0.f;
#pragma unroll
        for (int k = 0; k < HID; k++) acc += sx[nn][k] * sW[k * OUT_F + cc];
        int node = base + nn;
        zs[(size_t)node * OUT_F + cc] = acc * dinv[node];
    }
}

// ======================= gather layer 2: z[i] = zs[i] + sum_{s in N(i)} zs[s] =======================
__global__ __launch_bounds__(256) void k_gather2(const int* __restrict__ offs,
                                                 const int* __restrict__ deg,
                                                 const int* __restrict__ csr,
                                                 const float* __restrict__ zs,
                                                 float* __restrict__ z, int n) {
    int t = blockIdx.x * 256 + threadIdx.x;
    int node = t >> 4;          // 16 threads per node
    int cg = t & 15;            // 10 active float4 column-groups
    if (node >= n || cg >= 10) return;
    int o = offs[node], cnt = deg[node];
    size_t col = (size_t)cg * 4;
    float4 acc = *(const float4*)(zs + (size_t)node * OUT_F + col);  // self-loop term
    int k = o, kend = o + cnt;
    for (; k + 1 < kend; k += 2) {
        int s0 = csr[k], s1 = csr[k + 1];
        const float4 v0 = *(const float4*)(zs + (size_t)s0 * OUT_F + col);
        const float4 v1 = *(const float4*)(zs + (size_t)s1 * OUT_F + col);
        acc.x += v0.x + v1.x; acc.y += v0.y + v1.y;
        acc.z += v0.z + v1.z; acc.w += v0.w + v1.w;
    }
    if (k < kend) {
        int s0 = csr[k];
        const float4 v0 = *(const float4*)(zs + (size_t)s0 * OUT_F + col);
        acc.x += v0.x; acc.y += v0.y; acc.z += v0.z; acc.w += v0.w;
    }
    *(float4*)(z + (size_t)node * OUT_F + col) = acc;
}

// ======================= logits = log_softmax(z * dinv[row] + b2) =======================
__global__ __launch_bounds__(256) void k_logsoftmax(const float* __restrict__ z,
                                                    const float* __restrict__ dinv,
                                                    const float* __restrict__ b2,
                                                    float* __restrict__ out, int n) {
    int lane = threadIdx.x & 63;
    int node = blockIdx.x * 4 + (threadIdx.x >> 6);
    if (node >= n) return;
    float v = -INFINITY;
    if (lane < OUT_F) v = z[(size_t)node * OUT_F + lane] * dinv[node] + b2[lane];
    float m = v;
    for (int off = 32; off; off >>= 1) m = fmaxf(m, __shfl_xor(m, off));
    float ex = (lane < OUT_F) ? expf(v - m) : 0.0f;
    float s = ex;
    for (int off = 32; off; off >>= 1) s += __shfl_xor(s, off);
    float ls = logf(s);
    if (lane < OUT_F) out[(size_t)node * OUT_F + lane] = v - m - ls;
}

// ======================= mask MLP =======================
__global__ __launch_bounds__(256) void k_mask(const float* __restrict__ h,
                                              const float* __restrict__ Wm1,
                                              const float* __restrict__ bm1,
                                              const float* __restrict__ Wm2,
                                              const float* __restrict__ bm2,
                                              float* __restrict__ prob_out,
                                              float* __restrict__ mask_out, int n) {
    __shared__ float sW[HID * MASKD];  // 24 KB
    __shared__ float sh[4][HID];
    int tid = threadIdx.x;
    for (int i = tid; i < HID * MASKD; i += 256) sW[i] = Wm1[i];
    int wv = tid >> 6, lane = tid & 63;
    int nb = blockIdx.x * 4;
    if (nb >= n) return;
    int nt = min(4, n - nb);
    __syncthreads();
    for (int i = tid; i < nt * HID; i += 256)
        sh[i / HID][i % HID] = h[(size_t)(nb + i / HID) * HID + (i % HID)];
    __syncthreads();
    if (wv < nt) {
        float acc = bm1[lane];
#pragma unroll
        for (int k = 0; k < HID; k++) acc += sh[wv][k] * sW[k * MASKD + lane];
        float mrelu = fmaxf(acc, 0.0f);
        float part = mrelu * Wm2[lane];
        for (int off = 32; off; off >>= 1) part += __shfl_xor(part, off);
        if (lane == 0) {
            float t = part + bm2[0];
            float p = 1.0f / (1.0f + expf(-t));
            prob_out[nb + wv] = p;
            mask_out[nb + wv] = (p > 0.5f) ? 1.0f : 0.0f;
        }
    }
}

extern "C" void kernel_launch(void* const* d_in, const int* in_sizes, int n_in,
                              void* d_out, int out_size, void* d_ws, size_t ws_size,
                              hipStream_t stream) {
    const float* x   = (const float*)d_in[0];
    const int*   ei  = (const int*)d_in[1];
    const float* W1  = (const float*)d_in[2];
    const float* b1  = (const float*)d_in[3];
    const float* W2  = (const float*)d_in[4];
    const float* b2  = (const float*)d_in[5];
    const float* Wm1 = (const float*)d_in[6];
    const float* bm1 = (const float*)d_in[7];
    const float* Wm2 = (const float*)d_in[8];
    const float* bm2 = (const float*)d_in[9];

    int n = in_sizes[0] / IN_F;      // 50000
    int e = in_sizes[1] / 2;         // 800000
    const int* srcp = ei;            // edge_index[0]
    const int* dstp = ei + e;        // edge_index[1]

    // workspace layout
    float* ws   = (float*)d_ws;
    float* dinv = ws;                             // N
    float* hs   = dinv + n;                       // N*96  (pre-scaled linear output)
    float* h    = hs + (size_t)n * HID;           // N*96  (aggregated -> relu'd)
    float* zs   = h + (size_t)n * HID;            // N*40
    float* z    = zs + (size_t)n * OUT_F;         // N*40
    int* deg    = (int*)(z + (size_t)n * OUT_F);  // N (edge-only degree)
    int* offs   = deg + n;                        // N
    int* cursor = offs + n;                       // N
    int* bsum   = cursor + n;                     // 256
    int* csr    = bsum + 256;                     // E

    float* out    = (float*)d_out;
    float* logits = out;                          // N*40
    float* prob   = out + (size_t)n * OUT_F;      // N
    float* mask   = prob + n;                     // N

    int nb = (n + 255) / 256;   // 196 <= 256: two-level scan suffices

    k_zero_int  <<<nb, 256, 0, stream>>>(deg, n);
    k_count     <<<(e + 255) / 256, 256, 0, stream>>>(dstp, deg, e);
    k_dinv      <<<nb, 256, 0, stream>>>(deg, dinv, n);
    k_scan1     <<<nb, 256, 0, stream>>>(deg, offs, bsum, n);
    k_scan2     <<<1, 256, 0, stream>>>(bsum, nb);
    k_scan3     <<<nb, 256, 0, stream>>>(offs, bsum, cursor, n);
    k_fill      <<<(e + 255) / 256, 256, 0, stream>>>(srcp, dstp, cursor, csr, e);
    k_gemm1     <<<(n + 15) / 16, 256, 0, stream>>>(x, W1, dinv, hs, n);
    k_gather1   <<<(n * 32 + 255) / 256, 256, 0, stream>>>(offs, deg, csr, hs, h, n);
    k_relu_eps  <<<(n * HID + 255) / 256, 256, 0, stream>>>(h, dinv, b1, n);
    k_gemm2     <<<(n + 15) / 16, 256, 0, stream>>>(h, W2, dinv, zs, n);
    k_gather2   <<<(n * 16 + 255) / 256, 256, 0, stream>>>(offs, deg, csr, zs, z, n);
    k_logsoftmax<<<(n + 3) / 4, 256, 0, stream>>>(z, dinv, b2, logits, n);
    k_mask      <<<(n + 3) / 4, 256, 0, stream>>>(h, Wm1, bm1, Wm2, bm2, prob, mask, n);
}